// Round 4
// baseline (248.880 us; speedup 1.0000x reference)
//
#include <hip/hip_runtime.h>
#include <math.h>

#define NB 4096
#define ND 1024
#define SCALEF 20.0f
#define TILES 32   // 4096 / 128 tiles per dimension
#define GRID (TILES * TILES)
// epilogue compensation: elements scaled by 256 at convert -> dot x 65536
#define EPI_SCALE (SCALEF / 65536.0f)

typedef float floatx4 __attribute__((ext_vector_type(4)));
typedef long longx2 __attribute__((ext_vector_type(2)));

__device__ __forceinline__ void load16_to_lds(const void* g, void* l) {
    __builtin_amdgcn_global_load_lds(
        (const __attribute__((address_space(1))) void*)g,
        (__attribute__((address_space(3))) void*)l, 16, 0, 0);
}

// ---------------------------------------------------------------------------
// Kernel 1: fused L2-normalize + scale-by-256 + fp32->fp8(e4m3 OCP) convert,
// writing a PERMUTED row layout ready for MFMA fragment reads:
//   row byte position of element k  =  q*256 + s*8 + j
// where k = s*32 + q*8 + j  (s = K32 step, q = quad, j = 0..7).
// A ds_read_b128 at (q*256 + s*8) then yields the lane's 8-byte fp8 operand
// for steps s and s+1 in .x/.y of a long2. One wave per row.
// Also zeroes rowsum[] and the finalize counter.
// ---------------------------------------------------------------------------
__global__ __launch_bounds__(256) void mnrl_norm_cvt(
    const float* __restrict__ A, const float* __restrict__ P,
    unsigned char* __restrict__ A8, unsigned char* __restrict__ P8,
    float* __restrict__ rowsum, int* __restrict__ counter) {
    int row = blockIdx.x * 4 + (threadIdx.x >> 6);  // 0..8191
    int lane = threadIdx.x & 63;
    bool is_a = row < NB;
    const float* src = is_a ? (A + (size_t)row * ND)
                            : (P + (size_t)(row - NB) * ND);
    unsigned char* dst = is_a ? (A8 + (size_t)row * ND)
                              : (P8 + (size_t)(row - NB) * ND);

    // lane handles chunks c = lane and c = 64+lane; chunk c covers the 8
    // consecutive global k = (c>>2)*32 + (c&3)*8 .. +7  (one (s,q) cell).
    float4 v[2][2];
    float ss = 0.0f;
#pragma unroll
    for (int i = 0; i < 2; ++i) {
        int c = i * 64 + lane;
        int k0 = (c >> 2) * 32 + (c & 3) * 8;
        v[i][0] = *(const float4*)(src + k0);
        v[i][1] = *(const float4*)(src + k0 + 4);
        ss += v[i][0].x * v[i][0].x + v[i][0].y * v[i][0].y +
              v[i][0].z * v[i][0].z + v[i][0].w * v[i][0].w +
              v[i][1].x * v[i][1].x + v[i][1].y * v[i][1].y +
              v[i][1].z * v[i][1].z + v[i][1].w * v[i][1].w;
    }
#pragma unroll
    for (int off = 32; off > 0; off >>= 1) ss += __shfl_xor(ss, off, 64);
    float inv = 256.0f / fmaxf(sqrtf(ss), 1e-8f);  // 256x folded in here

#pragma unroll
    for (int i = 0; i < 2; ++i) {
        int c = i * 64 + lane;
        int pos = (c & 3) * 256 + (c >> 2) * 8;  // q*256 + s*8
        int lo = __builtin_amdgcn_cvt_pk_fp8_f32(v[i][0].x * inv, v[i][0].y * inv, 0, false);
        lo = __builtin_amdgcn_cvt_pk_fp8_f32(v[i][0].z * inv, v[i][0].w * inv, lo, true);
        int hi = __builtin_amdgcn_cvt_pk_fp8_f32(v[i][1].x * inv, v[i][1].y * inv, 0, false);
        hi = __builtin_amdgcn_cvt_pk_fp8_f32(v[i][1].z * inv, v[i][1].w * inv, hi, true);
        int2 w; w.x = lo; w.y = hi;
        *(int2*)(dst + pos) = w;
    }
    if (is_a && lane == 0) rowsum[row] = 0.0f;
    if (blockIdx.x == 0 && threadIdx.x == 0) *counter = 0;
}

// ---------------------------------------------------------------------------
// Kernel 2: 128x128-tile fp8 MFMA GEMM + fused exp-sum + diag + last-block
// finalize. BK=64 (2 K32 steps/iter), single-buffered R2 structure (the
// proven 2-barrier loop). LDS per matrix per iter: 128 rows x 64 B.
// Swizzle: 16-B chunk q of row R lives at slot q ^ ((R>>1)&3). Under the
// 8-lane-phase service model (consecutive 8 lanes per cycle), both the DMA
// write (linear lane*16) and the frag read (slots hit all 8 bank groups per
// phase) are conflict-free.
// ---------------------------------------------------------------------------
__global__ __launch_bounds__(256) void mnrl_gemm_lse(
    const unsigned char* __restrict__ A8, const unsigned char* __restrict__ P8,
    float* __restrict__ rowsum, float* __restrict__ diag,
    int* __restrict__ counter, float* __restrict__ out) {
    __shared__ __align__(16) unsigned char lds_a[128 * 64];
    __shared__ __align__(16) unsigned char lds_b[128 * 64];

    // GROUP_M=8 swizzle for L2 locality
    int pid = blockIdx.x;
    const int num_in_group = 8 * TILES;
    int group_id = pid / num_in_group;
    int tile_m = group_id * 8 + (pid % 8);
    int tile_n = (pid % num_in_group) / 8;

    int t = threadIdx.x;
    int lane = t & 63;
    int wave = t >> 6;
    int wm = wave >> 1, wn = wave & 1;
    int quad = lane >> 4;
    int l16 = lane & 15;

    const unsigned char* Abase = A8 + (size_t)tile_m * 128 * ND;
    const unsigned char* Pbase = P8 + (size_t)tile_n * 128 * ND;

    // Staging: issue j covers rows j*16..j*16+15 (1024 B). Lane l writes HW
    // slot l&3 of row rl = l>>2; fetch chunk q so slot = q ^ ((R>>1)&3):
    int rl = lane >> 2;
    int qsw = (lane & 3) ^ ((lane >> 3) & 3);       // chunk to fetch
    // Frag read slot for row R = wm*64 + mt*16 + l16: ((R>>1)&3) = (l16>>1)&3
    int rslot = (quad ^ ((l16 >> 1) & 3)) * 16;     // byte offset of my b128

    floatx4 acc[4][4];
#pragma unroll
    for (int i = 0; i < 4; ++i)
#pragma unroll
        for (int j = 0; j < 4; ++j) acc[i][j] = (floatx4){0.f, 0.f, 0.f, 0.f};

    for (int it = 0; it < ND / 64; ++it) {
        __syncthreads();  // frag reads of previous iter complete
#pragma unroll
        for (int jj = 0; jj < 2; ++jj) {
            int j = wave * 2 + jj;  // 0..7
            size_t goff = (size_t)(j * 16 + rl) * ND + qsw * 256 + it * 16;
            load16_to_lds(Abase + goff, lds_a + j * 1024);
            load16_to_lds(Pbase + goff, lds_b + j * 1024);
        }
        __syncthreads();  // drains vmcnt(0): staged data visible

        longx2 af[4], bfr[4];
#pragma unroll
        for (int mt = 0; mt < 4; ++mt) {
            int R = wm * 64 + mt * 16 + l16;
            af[mt] = *(const longx2*)&lds_a[R * 64 + rslot];
        }
#pragma unroll
        for (int nt = 0; nt < 4; ++nt) {
            int R = wn * 64 + nt * 16 + l16;
            bfr[nt] = *(const longx2*)&lds_b[R * 64 + rslot];
        }
        // .x = K32 step 2*it, .y = step 2*it+1
#pragma unroll
        for (int mt = 0; mt < 4; ++mt)
#pragma unroll
            for (int nt = 0; nt < 4; ++nt)
                acc[mt][nt] = __builtin_amdgcn_mfma_f32_16x16x32_fp8_fp8(
                    af[mt].x, bfr[nt].x, acc[mt][nt], 0, 0, 0);
#pragma unroll
        for (int mt = 0; mt < 4; ++mt)
#pragma unroll
            for (int nt = 0; nt < 4; ++nt)
                acc[mt][nt] = __builtin_amdgcn_mfma_f32_16x16x32_fp8_fp8(
                    af[mt].y, bfr[nt].y, acc[mt][nt], 0, 0, 0);
    }

    // Epilogue. C/D layout: col = l16, row = quad*4 + reg.
    int row0 = tile_m * 128 + wm * 64;
    int col0 = tile_n * 128 + wn * 64;
    bool diag_block = (tile_m == tile_n);

    float psum[4][4];
#pragma unroll
    for (int mt = 0; mt < 4; ++mt)
#pragma unroll
        for (int r = 0; r < 4; ++r) psum[mt][r] = 0.0f;

#pragma unroll
    for (int mt = 0; mt < 4; ++mt) {
#pragma unroll
        for (int nt = 0; nt < 4; ++nt) {
#pragma unroll
            for (int r = 0; r < 4; ++r) {
                float sc = EPI_SCALE * acc[mt][nt][r];
                psum[mt][r] += __expf(sc - SCALEF);  // scores in [-20,20]
                if (diag_block) {
                    int grow = row0 + mt * 16 + quad * 4 + r;
                    int gcol = col0 + nt * 16 + l16;
                    if (grow == gcol) diag[grow] = sc;
                }
            }
        }
    }

#pragma unroll
    for (int mt = 0; mt < 4; ++mt) {
#pragma unroll
        for (int r = 0; r < 4; ++r) {
            float v = psum[mt][r];
            v += __shfl_xor(v, 1, 64);
            v += __shfl_xor(v, 2, 64);
            v += __shfl_xor(v, 4, 64);
            v += __shfl_xor(v, 8, 64);
            if (l16 == 0) atomicAdd(&rowsum[row0 + mt * 16 + quad * 4 + r], v);
        }
    }

    // -------- fused finalize: last block computes the loss ----------------
    __threadfence();
    __shared__ int is_last;
    if (t == 0) {
        int old = __hip_atomic_fetch_add(counter, 1, __ATOMIC_ACQ_REL,
                                         __HIP_MEMORY_SCOPE_AGENT);
        is_last = (old == GRID - 1);
    }
    __syncthreads();
    if (is_last) {
        float local = 0.0f;
        for (int i = t; i < NB; i += 256) {
            float rs = __hip_atomic_load(&rowsum[i], __ATOMIC_RELAXED,
                                         __HIP_MEMORY_SCOPE_AGENT);
            float dg = __hip_atomic_load(&diag[i], __ATOMIC_RELAXED,
                                         __HIP_MEMORY_SCOPE_AGENT);
            local += (logf(rs) + SCALEF) - dg;
        }
#pragma unroll
        for (int off = 32; off > 0; off >>= 1) local += __shfl_down(local, off, 64);
        __shared__ float sred[4];
        if ((t & 63) == 0) sred[t >> 6] = local;
        __syncthreads();
        if (t == 0) out[0] = (sred[0] + sred[1] + sred[2] + sred[3]) / (float)NB;
    }
}

// ---------------------------------------------------------------------------
extern "C" void kernel_launch(void* const* d_in, const int* in_sizes, int n_in,
                              void* d_out, int out_size, void* d_ws, size_t ws_size,
                              hipStream_t stream) {
    const float* A = (const float*)d_in[0];
    const float* P = (const float*)d_in[1];

    unsigned char* A8 = (unsigned char*)d_ws;           // 4 MiB (permuted fp8)
    unsigned char* P8 = A8 + (size_t)NB * ND;           // 4 MiB
    float* rowsum = (float*)(P8 + (size_t)NB * ND);     // 16 KiB
    float* diag = rowsum + NB;                          // 16 KiB
    int* counter = (int*)(diag + NB);                   // 4 B

    mnrl_norm_cvt<<<2 * NB / 4, 256, 0, stream>>>(A, P, A8, P8, rowsum, counter);
    mnrl_gemm_lse<<<GRID, 256, 0, stream>>>(A8, P8, rowsum, diag, counter,
                                            (float*)d_out);
}

// Round 5
// 198.416 us; speedup vs baseline: 1.2543x; 1.2543x over previous
//
#include <hip/hip_runtime.h>
#include <math.h>

#define NB 4096
#define ND 1024
#define SCALEF 20.0f
#define TILES 32   // 4096 / 128 tiles per dimension
#define GRID (TILES * TILES)
// epilogue compensation: elements scaled by 256 at convert -> dot x 65536
#define EPI_SCALE (SCALEF / 65536.0f)

typedef float floatx4 __attribute__((ext_vector_type(4)));
typedef long longx2 __attribute__((ext_vector_type(2)));

__device__ __forceinline__ void load16_to_lds(const void* g, void* l) {
    __builtin_amdgcn_global_load_lds(
        (const __attribute__((address_space(1))) void*)g,
        (__attribute__((address_space(3))) void*)l, 16, 0, 0);
}

// ---------------------------------------------------------------------------
// Kernel 1: fused L2-normalize + scale-by-256 + fp32->fp8(e4m3 OCP) convert.
// Permuted row layout, ITERATION-CONTIGUOUS: element k = s*32 + q*8 + j
// (s = K32 step, q = quad, j = 0..7) lives at byte
//   pos(k) = (s>>1)*64 + q*16 + (s&1)*8 + j
// so a 16-B cell holds one quad's operands for steps 2sp and 2sp+1, and a
// GEMM iteration (BK=128 = 2 sp) reads a contiguous 128-B row segment.
// One wave per row; lane l handles cell l (sp=l>>2, q=l&3): reads two
// float4 pairs, writes one int4 at row+l*16 (fully coalesced both sides).
// Also zeroes rowsum[] and the finalize counter.
// ---------------------------------------------------------------------------
__global__ __launch_bounds__(256) void mnrl_norm_cvt(
    const float* __restrict__ A, const float* __restrict__ P,
    unsigned char* __restrict__ A8, unsigned char* __restrict__ P8,
    float* __restrict__ rowsum, int* __restrict__ counter) {
    int row = blockIdx.x * 4 + (threadIdx.x >> 6);  // 0..8191
    int lane = threadIdx.x & 63;
    bool is_a = row < NB;
    const float* src = is_a ? (A + (size_t)row * ND)
                            : (P + (size_t)(row - NB) * ND);
    unsigned char* dst = is_a ? (A8 + (size_t)row * ND)
                              : (P8 + (size_t)(row - NB) * ND);

    int g0 = (lane >> 2) * 64 + (lane & 3) * 8;  // k of step 2sp, quad q
    float4 va = *(const float4*)(src + g0);
    float4 vb = *(const float4*)(src + g0 + 4);
    float4 vc = *(const float4*)(src + g0 + 32);  // step 2sp+1
    float4 vd = *(const float4*)(src + g0 + 36);

    float ss = va.x * va.x + va.y * va.y + va.z * va.z + va.w * va.w +
               vb.x * vb.x + vb.y * vb.y + vb.z * vb.z + vb.w * vb.w +
               vc.x * vc.x + vc.y * vc.y + vc.z * vc.z + vc.w * vc.w +
               vd.x * vd.x + vd.y * vd.y + vd.z * vd.z + vd.w * vd.w;
#pragma unroll
    for (int off = 32; off > 0; off >>= 1) ss += __shfl_xor(ss, off, 64);
    float inv = 256.0f / fmaxf(sqrtf(ss), 1e-8f);  // 256x folded in here

    int w0 = __builtin_amdgcn_cvt_pk_fp8_f32(va.x * inv, va.y * inv, 0, false);
    w0 = __builtin_amdgcn_cvt_pk_fp8_f32(va.z * inv, va.w * inv, w0, true);
    int w1 = __builtin_amdgcn_cvt_pk_fp8_f32(vb.x * inv, vb.y * inv, 0, false);
    w1 = __builtin_amdgcn_cvt_pk_fp8_f32(vb.z * inv, vb.w * inv, w1, true);
    int w2 = __builtin_amdgcn_cvt_pk_fp8_f32(vc.x * inv, vc.y * inv, 0, false);
    w2 = __builtin_amdgcn_cvt_pk_fp8_f32(vc.z * inv, vc.w * inv, w2, true);
    int w3 = __builtin_amdgcn_cvt_pk_fp8_f32(vd.x * inv, vd.y * inv, 0, false);
    w3 = __builtin_amdgcn_cvt_pk_fp8_f32(vd.z * inv, vd.w * inv, w3, true);
    int4 w; w.x = w0; w.y = w1; w.z = w2; w.w = w3;
    *(int4*)(dst + lane * 16) = w;

    if (is_a && lane == 0) rowsum[row] = 0.0f;
    if (blockIdx.x == 0 && threadIdx.x == 0) *counter = 0;
}

// ---------------------------------------------------------------------------
// Kernel 2: 128x128-tile fp8 MFMA GEMM + fused exp-sum + diag + last-block
// finalize. BK=128 (4 K32 steps / 2 sp-cells per iter, 8 iters), proven
// 2-barrier single-buffer loop. LDS: 2 x 16 KB.
// DMA: 8 consecutive lanes fetch one row's contiguous 128-B segment,
// permuted so chunk c lands at slot c^(row&7)  (lane l fetches chunk
// (l&7)^(l>>3)). Frag read slot = (spl*4+quad)^(l16&7): per 8-lane phase,
// bank group = slot mod 8 = XOR bijection -> conflict-free (R4-verified
// swizzle family, now with ideal global coalescing).
// ---------------------------------------------------------------------------
__global__ __launch_bounds__(256) void mnrl_gemm_lse(
    const unsigned char* __restrict__ A8, const unsigned char* __restrict__ P8,
    float* __restrict__ rowsum, float* __restrict__ diag,
    int* __restrict__ counter, float* __restrict__ out) {
    __shared__ __align__(16) unsigned char lds_a[128 * 128];
    __shared__ __align__(16) unsigned char lds_b[128 * 128];

    // GROUP_M=8 swizzle for L2 locality
    int pid = blockIdx.x;
    const int num_in_group = 8 * TILES;
    int group_id = pid / num_in_group;
    int tile_m = group_id * 8 + (pid % 8);
    int tile_n = (pid % num_in_group) / 8;

    int t = threadIdx.x;
    int lane = t & 63;
    int wave = t >> 6;
    int wm = wave >> 1, wn = wave & 1;
    int quad = lane >> 4;
    int l16 = lane & 15;

    const unsigned char* Abase = A8 + (size_t)tile_m * 128 * ND;
    const unsigned char* Pbase = P8 + (size_t)tile_n * 128 * ND;

    // DMA addressing: issue ji covers rows ji*8..+8. Lane l -> row-in-issue
    // rl = l>>3 (HW slot l&7 of that row); fetch chunk (l&7)^rl so that
    // slot s of row r holds chunk s^(r&7).
    int rl = lane >> 3;
    int chsw = ((lane & 7) ^ rl) * 16;   // byte offset of fetched chunk
    int sw7 = l16 & 7;                   // frag-read swizzle key

    floatx4 acc[4][4];
#pragma unroll
    for (int i = 0; i < 4; ++i)
#pragma unroll
        for (int j = 0; j < 4; ++j) acc[i][j] = (floatx4){0.f, 0.f, 0.f, 0.f};

    for (int it = 0; it < ND / 128; ++it) {
        __syncthreads();  // frag reads of previous iter complete
#pragma unroll
        for (int jj = 0; jj < 4; ++jj) {
            int ji = wave * 4 + jj;  // 0..15
            size_t goff = (size_t)(ji * 8 + rl) * ND + it * 128 + chsw;
            load16_to_lds(Abase + goff, lds_a + ji * 1024);
            load16_to_lds(Pbase + goff, lds_b + ji * 1024);
        }
        __syncthreads();  // drains vmcnt(0): staged data visible

#pragma unroll
        for (int spl = 0; spl < 2; ++spl) {
            int slot = ((spl * 4 + quad) ^ sw7) * 16;
            longx2 af[4], bfr[4];
#pragma unroll
            for (int mt = 0; mt < 4; ++mt) {
                int R = wm * 64 + mt * 16 + l16;
                af[mt] = *(const longx2*)&lds_a[R * 128 + slot];
            }
#pragma unroll
            for (int nt = 0; nt < 4; ++nt) {
                int R = wn * 64 + nt * 16 + l16;
                bfr[nt] = *(const longx2*)&lds_b[R * 128 + slot];
            }
            // .x = K32 step 2*(it*2+spl), .y = the next step
#pragma unroll
            for (int mt = 0; mt < 4; ++mt)
#pragma unroll
                for (int nt = 0; nt < 4; ++nt)
                    acc[mt][nt] = __builtin_amdgcn_mfma_f32_16x16x32_fp8_fp8(
                        af[mt].x, bfr[nt].x, acc[mt][nt], 0, 0, 0);
#pragma unroll
            for (int mt = 0; mt < 4; ++mt)
#pragma unroll
                for (int nt = 0; nt < 4; ++nt)
                    acc[mt][nt] = __builtin_amdgcn_mfma_f32_16x16x32_fp8_fp8(
                        af[mt].y, bfr[nt].y, acc[mt][nt], 0, 0, 0);
        }
    }

    // Epilogue. C/D layout: col = l16, row = quad*4 + reg.
    int row0 = tile_m * 128 + wm * 64;
    int col0 = tile_n * 128 + wn * 64;
    bool diag_block = (tile_m == tile_n);

    float psum[4][4];
#pragma unroll
    for (int mt = 0; mt < 4; ++mt)
#pragma unroll
        for (int r = 0; r < 4; ++r) psum[mt][r] = 0.0f;

#pragma unroll
    for (int mt = 0; mt < 4; ++mt) {
#pragma unroll
        for (int nt = 0; nt < 4; ++nt) {
#pragma unroll
            for (int r = 0; r < 4; ++r) {
                float sc = EPI_SCALE * acc[mt][nt][r];
                psum[mt][r] += __expf(sc - SCALEF);  // scores in [-20,20]
                if (diag_block) {
                    int grow = row0 + mt * 16 + quad * 4 + r;
                    int gcol = col0 + nt * 16 + l16;
                    if (grow == gcol) diag[grow] = sc;
                }
            }
        }
    }

#pragma unroll
    for (int mt = 0; mt < 4; ++mt) {
#pragma unroll
        for (int r = 0; r < 4; ++r) {
            float v = psum[mt][r];
            v += __shfl_xor(v, 1, 64);
            v += __shfl_xor(v, 2, 64);
            v += __shfl_xor(v, 4, 64);
            v += __shfl_xor(v, 8, 64);
            if (l16 == 0) atomicAdd(&rowsum[row0 + mt * 16 + quad * 4 + r], v);
        }
    }

    // -------- fused finalize: last block computes the loss ----------------
    __threadfence();
    __shared__ int is_last;
    if (t == 0) {
        int old = __hip_atomic_fetch_add(counter, 1, __ATOMIC_ACQ_REL,
                                         __HIP_MEMORY_SCOPE_AGENT);
        is_last = (old == GRID - 1);
    }
    __syncthreads();
    if (is_last) {
        float local = 0.0f;
        for (int i = t; i < NB; i += 256) {
            float rs = __hip_atomic_load(&rowsum[i], __ATOMIC_RELAXED,
                                         __HIP_MEMORY_SCOPE_AGENT);
            float dg = __hip_atomic_load(&diag[i], __ATOMIC_RELAXED,
                                         __HIP_MEMORY_SCOPE_AGENT);
            local += (logf(rs) + SCALEF) - dg;
        }
#pragma unroll
        for (int off = 32; off > 0; off >>= 1) local += __shfl_down(local, off, 64);
        __shared__ float sred[4];
        if ((t & 63) == 0) sred[t >> 6] = local;
        __syncthreads();
        if (t == 0) out[0] = (sred[0] + sred[1] + sred[2] + sred[3]) / (float)NB;
    }
}

// ---------------------------------------------------------------------------
extern "C" void kernel_launch(void* const* d_in, const int* in_sizes, int n_in,
                              void* d_out, int out_size, void* d_ws, size_t ws_size,
                              hipStream_t stream) {
    const float* A = (const float*)d_in[0];
    const float* P = (const float*)d_in[1];

    unsigned char* A8 = (unsigned char*)d_ws;           // 4 MiB (permuted fp8)
    unsigned char* P8 = A8 + (size_t)NB * ND;           // 4 MiB
    float* rowsum = (float*)(P8 + (size_t)NB * ND);     // 16 KiB
    float* diag = rowsum + NB;                          // 16 KiB
    int* counter = (int*)(diag + NB);                   // 4 B

    mnrl_norm_cvt<<<2 * NB / 4, 256, 0, stream>>>(A, P, A8, P8, rowsum, counter);
    mnrl_gemm_lse<<<GRID, 256, 0, stream>>>(A8, P8, rowsum, diag, counter,
                                            (float*)d_out);
}